// Round 1
// baseline (429.988 us; speedup 1.0000x reference)
//
#include <hip/hip_runtime.h>

// LIF spike scan over time (innermost axis), one thread per neuron.
// x: [N_neurons=524288, T=100] fp32 row-major; out: same shape, spikes in {0,1}.
//
// Numerics: must match numpy's separately-rounded  mem = (mem*DECAY)*(1-spike) + xi
// exactly — output is a threshold comparison, so a 1-ulp FMA contraction flips
// spikes. __fmul_rn/__fadd_rn are never contracted by the compiler.

#define THRESH 0.5f
#define DECAY  0.2f

constexpr int T  = 100;
constexpr int TV = T / 4;  // 25 float4 chunks; 400 B per neuron, 16B-aligned

__global__ __launch_bounds__(256) void lif_kernel(const float* __restrict__ x,
                                                  float* __restrict__ out,
                                                  int n_neurons) {
    int n = blockIdx.x * blockDim.x + threadIdx.x;
    if (n >= n_neurons) return;

    const float4* xp = reinterpret_cast<const float4*>(x + (size_t)n * T);
    float4*       op = reinterpret_cast<float4*>(out + (size_t)n * T);

    float mem = 0.0f;
    float spike = 0.0f;

#pragma unroll
    for (int c = 0; c < TV; ++c) {
        float4 xi = xp[c];
        float4 o;
        // One LIF step, rounding-exact vs numpy:
        //   mem   = ((mem * DECAY) * (1 - spike)) + xi
        //   spike = mem > THRESH ? 1 : 0
#define STEP(comp)                                                              \
        mem = __fadd_rn(__fmul_rn(__fmul_rn(mem, DECAY),                        \
                                  __fsub_rn(1.0f, spike)), xi.comp);            \
        spike = (mem > THRESH) ? 1.0f : 0.0f;                                   \
        o.comp = spike;
        STEP(x) STEP(y) STEP(z) STEP(w)
#undef STEP
        op[c] = o;
    }
}

extern "C" void kernel_launch(void* const* d_in, const int* in_sizes, int n_in,
                              void* d_out, int out_size, void* d_ws, size_t ws_size,
                              hipStream_t stream) {
    const float* x   = (const float*)d_in[0];
    float*       out = (float*)d_out;

    int n_neurons = in_sizes[0] / T;  // 128*4096 = 524288
    int block = 256;
    int grid  = (n_neurons + block - 1) / block;

    lif_kernel<<<grid, block, 0, stream>>>(x, out, n_neurons);
}